// Round 3
// baseline (420.848 us; speedup 1.0000x reference)
//
#include <hip/hip_runtime.h>
#include <hip/hip_bf16.h>

#define NPTS 8192
#define KNN 64
#define EPSF 1e-7f

// ---------------- workspace layout (float offsets) ----------------
#define OFF_P4      0              // packed (x,y,z,rr) float4 per point: 4*N
#define OFF_STATS   32768          // s1:+0(128) s2:+128(256) s3:+384(512) s4:+896(2048) = 2944
#define OFF_PART    36012          // 32 blocks x 2 u64 = 128 floats
#define OFF_FEATDN  36864          // N*4 -> 69632
#define OFF_WT1     69632          // 4*64 fp32 transposed -> 69888
#define OFF_GWT     69888          // MLP bf16 weights: 18432 shorts = 9216 -> 79104
#define OFF_BW2     79104          // c2w bf16: 8192 shorts = 4096 -> 83200
#define OFF_BW3     83200          // c3w bf16: 49152 shorts = 24576 -> 107776
#define OFF_BW4     107776         // c4w bf16: 262144 shorts = 131072 -> 238848
#define OFF_XB1     238848         // bf16 [8192][64]  = 262144 fl -> 500992
#define OFF_XB3     500992         // bf16 [8192][192] = 786432 fl -> 1287424
#define OFF_XB4     1287424        // bf16 [8192][256] = 1048576 fl -> 2336000
#define OFF_Y1      2336000        // 64*N fp32 -> 2860288 (dead after bnpack1; reused below)
#define OFF_Y2      2860288        // 128*N fp32 -> 3908864 (dead after bnpack2; reused below)
#define OFF_Y3      3908864        // 256*N fp32 -> 6006016
#define OFF_FEATUP  6006016        // N*K*4 fp32 -> 8103168 (~30.9 MB)
// reuse of dead regions:
#define OFF_S4      OFF_Y1                 // 256x256 fp32 = 65536
#define OFF_MSUM    (OFF_Y1 + 65536)       // 256 fp32
#define OFF_SC4     (OFF_Y1 + 65792)       // 1024 fp32
#define OFF_SH4     (OFF_Y1 + 66816)       // 1024 fp32  (ends 2403840 < OFF_Y2)
#define OFF_XB4T    OFF_Y2                 // bf16 [256][8192] = 524288 fl (fits y2 region)

typedef __bf16 bf16x8 __attribute__((ext_vector_type(8)));
typedef float  f32x4  __attribute__((ext_vector_type(4)));

__device__ __forceinline__ unsigned f2u(float f) {
    unsigned u = __float_as_uint(f);
    return ((int)u >= 0) ? (u | 0x80000000u) : ~u;
}
__device__ __forceinline__ float key_to_f(unsigned long long k) {
    unsigned v = (unsigned)(k >> 32);
    unsigned ob = (v & 0x80000000u) ? (v ^ 0x80000000u) : ~v;
    return __uint_as_float(ob);
}
__device__ __forceinline__ unsigned short f2bf(float x) {
    unsigned u = __float_as_uint(x);
    unsigned r = (u + 0x7FFFu + ((u >> 16) & 1u)) >> 16;   // RNE
    return (unsigned short)r;
}
__device__ __forceinline__ float bf2f(unsigned short u) {
    return __uint_as_float((unsigned)u << 16);
}
__device__ __forceinline__ unsigned long long u64min(unsigned long long a, unsigned long long b){ return a < b ? a : b; }
__device__ __forceinline__ unsigned long long u64max(unsigned long long a, unsigned long long b){ return a < b ? b : a; }

__device__ __forceinline__ unsigned long long sort_merge(
    unsigned long long key, unsigned long long cur, int lane)
{
    #pragma unroll
    for (int k = 2; k <= 64; k <<= 1) {
        #pragma unroll
        for (int j = k >> 1; j > 0; j >>= 1) {
            unsigned long long o = __shfl_xor(key, j);
            bool up = ((lane & k) == 0);
            bool lower = ((lane & j) == 0);
            key = (lower == up) ? u64min(key, o) : u64max(key, o);
        }
    }
    unsigned long long rev = __shfl(key, 63 - lane);
    unsigned long long m = u64min(cur, rev);
    #pragma unroll
    for (int j = 32; j > 0; j >>= 1) {
        unsigned long long o = __shfl_xor(m, j);
        m = ((lane & j) == 0) ? u64min(m, o) : u64max(m, o);
    }
    return m;
}

// ---------------- prep A + weight prep (fused; disjoint work) ----------------
__global__ __launch_bounds__(256) void prepwt_kernel(
    const float* __restrict__ points,
    const float* __restrict__ c1w, const float* __restrict__ c2w,
    const float* __restrict__ c3w, const float* __restrict__ c4w,
    const float* __restrict__ gw0, const float* __restrict__ gw1,
    const float* __restrict__ gw2, const float* __restrict__ gw3,
    const float* __restrict__ gw4,
    float* __restrict__ ws)
{
    // ---- weight-prep part (all 256 blocks) ----
    const int t = blockIdx.x * 256 + threadIdx.x;
    const int T = 256 * 256;
    for (int m = t; m < 2944; m += T) ws[OFF_STATS + m] = 0.f;
    for (int m = t; m < 64*4; m += T) { int o = m >> 2, c = m & 3; ws[OFF_WT1 + c*64 + o] = c1w[m]; }

    unsigned short* bw2 = (unsigned short*)(ws + OFF_BW2);
    for (int m = t; m < 128*64; m += T)   bw2[m] = f2bf(c2w[m]);
    unsigned short* bw3 = (unsigned short*)(ws + OFF_BW3);
    for (int m = t; m < 256*192; m += T)  bw3[m] = f2bf(c3w[m]);
    unsigned short* bw4 = (unsigned short*)(ws + OFF_BW4);
    for (int m = t; m < 1024*256; m += T) bw4[m] = f2bf(c4w[m]);

    unsigned short* gwt = (unsigned short*)(ws + OFF_GWT);
    for (int m = t; m < 2048; m += T) {          // gw0T padded [64][32]
        int o = m >> 5, i = m & 31;
        gwt[m] = (i < 4) ? f2bf(gw0[i*64 + o]) : (unsigned short)0;
    }
    const float* gsrc[4] = {gw1, gw2, gw3, gw4};
    for (int l = 0; l < 4; ++l) {
        const float* g = gsrc[l];
        unsigned short* dst = gwt + 2048 + l*4096;
        for (int m = t; m < 4096; m += T) { int o = m >> 6, i = m & 63; dst[m] = f2bf(g[i*64 + o]); }
    }

    // ---- prep_a part (blocks 0..31 only; block-uniform branch) ----
    if (blockIdx.x < 32) {
        const int n = blockIdx.x * 256 + threadIdx.x;
        float x = points[3*n+0], y = points[3*n+1], z = points[3*n+2];
        float rr = x*x + y*y + z*z;
        ((float4*)(ws + OFF_P4))[n] = make_float4(x, y, z, rr);
        float vn = sqrtf(rr);
        unsigned b = __float_as_uint(vn);
        unsigned long long mxk = ((unsigned long long)b << 32) | (unsigned long long)(0xFFFFFFFFu - (unsigned)n);
        unsigned long long mnk = ((unsigned long long)b << 32) | (unsigned long long)(unsigned)n;
        for (int j = 32; j > 0; j >>= 1) {
            mxk = u64max(mxk, __shfl_xor(mxk, j));
            mnk = u64min(mnk, __shfl_xor(mnk, j));
        }
        __shared__ unsigned long long smx[4], smn[4];
        int wid = threadIdx.x >> 6;
        if ((threadIdx.x & 63) == 0) { smx[wid] = mxk; smn[wid] = mnk; }
        __syncthreads();
        if (threadIdx.x == 0) {
            unsigned long long MX = 0ull, MN = ~0ull;
            for (int i = 0; i < 4; ++i) { MX = u64max(MX, smx[i]); MN = u64min(MN, smn[i]); }
            unsigned long long* parts = (unsigned long long*)(ws + OFF_PART);
            parts[2*blockIdx.x + 0] = MX;
            parts[2*blockIdx.x + 1] = MN;
        }
    }
}

// ---------------- prep C: feat_down (prep_b reduce folded into per-block prologue) ----------------
__global__ __launch_bounds__(256) void prep_c_kernel(float* __restrict__ ws)
{
    __shared__ float av[9];
    const int tid = threadIdx.x;
    if (tid < 64) {
        const unsigned long long* parts = (const unsigned long long*)(ws + OFF_PART);
        unsigned long long mxk = (tid < 32) ? parts[2*tid + 0] : 0ull;
        unsigned long long mnk = (tid < 32) ? parts[2*tid + 1] : ~0ull;
        for (int j = 32; j > 0; j >>= 1) {
            mxk = u64max(mxk, __shfl_xor(mxk, j));
            mnk = u64min(mnk, __shfl_xor(mnk, j));
        }
        if (tid == 0) {
            int i1 = (int)(0xFFFFFFFFu - (unsigned)(mxk & 0xFFFFFFFFu));
            int i2 = (int)(unsigned)(mnk & 0xFFFFFFFFu);
            float4 p1 = ((const float4*)(ws + OFF_P4))[i1];
            float4 p2 = ((const float4*)(ws + OFF_P4))[i2];
            float n1 = sqrtf(p1.x*p1.x + p1.y*p1.y + p1.z*p1.z) + EPSF;
            float a1x = p1.x/n1, a1y = p1.y/n1, a1z = p1.z/n1;
            float n2 = sqrtf(p2.x*p2.x + p2.y*p2.y + p2.z*p2.z) + EPSF;
            float a2x = p2.x/n2, a2y = p2.y/n2, a2z = p2.z/n2;
            float a3x = a1x + 1.5f*a2x, a3y = a1y + 1.5f*a2y, a3z = a1z + 1.5f*a2z;
            float n3 = sqrtf(a3x*a3x + a3y*a3y + a3z*a3z) + EPSF;
            a3x /= n3; a3y /= n3; a3z /= n3;
            av[0]=a1x; av[1]=a1y; av[2]=a1z;
            av[3]=a2x; av[4]=a2y; av[5]=a2z;
            av[6]=a3x; av[7]=a3y; av[8]=a3z;
        }
    }
    __syncthreads();
    const int n = blockIdx.x * 256 + tid;
    float4 v = ((const float4*)(ws + OFF_P4))[n];
    float vn = sqrtf(v.w);
    float den = vn + EPSF;
    float f1 = (v.x*av[0] + v.y*av[1] + v.z*av[2]) / den;
    float f2 = (v.x*av[3] + v.y*av[4] + v.z*av[5]) / den;
    float f3 = (v.x*av[6] + v.y*av[7] + v.z*av[8]) / den;
    float4* f4 = (float4*)(ws + OFF_FEATDN + 4*n);
    *f4 = make_float4(f1, f2, f3, vn);
}

// ---------------- KNN + local rotation-invariant features ----------------
// 1 query per wave, 8 waves/block. Per-wave chunk ROTATION within the shared tile
// de-phases the queue-flush sorts across waves (top-64 selection is scan-order-invariant).
__global__ __launch_bounds__(512) void knn_feat_kernel(
    const float4* __restrict__ p4, float4* __restrict__ feat_up)
{
    __shared__ __align__(16) float4 scand[2048];
    __shared__ unsigned long long queue[8][128];
    const int lane = threadIdx.x & 63;
    const int wid  = threadIdx.x >> 6;
    const int q = blockIdx.x * 8 + wid;

    const float4 qa = p4[q];
    unsigned long long cur = ~0ull;
    float kthd = __builtin_inff();
    int qc = 0;
    unsigned long long* Q = queue[wid];

    for (int base = 0; base < NPTS; base += 2048) {
        __syncthreads();
        for (int t = threadIdx.x; t < 2048; t += 512) scand[t] = p4[base + t];
        __syncthreads();
        #pragma unroll 2
        for (int s = 0; s < 32; ++s) {
            const int sub = ((s + wid * 4) & 31) << 6;   // per-wave rotation
            float4 cd = scand[sub + lane];
            float dot = fmaf(qa.x, cd.x, fmaf(qa.y, cd.y, qa.z * cd.z));
            float d   = fmaf(-2.f, dot, qa.w) + cd.w;
            bool p = d < kthd;
            unsigned long long m = __ballot(p);
            if (m) {
                int prefix = __builtin_amdgcn_mbcnt_hi((unsigned)(m >> 32),
                              __builtin_amdgcn_mbcnt_lo((unsigned)m, 0));
                if (p) Q[qc + prefix] = ((unsigned long long)f2u(d) << 32)
                                      | (unsigned long long)(unsigned)(base + sub + lane);
                qc += __popcll(m);
                if (qc >= 64) {
                    qc -= 64;
                    cur = sort_merge(Q[qc + lane], cur, lane);
                    kthd = key_to_f(__shfl(cur, 63));
                }
            }
        }
    }
    cur = sort_merge((lane < qc) ? Q[lane] : ~0ull, cur, lane);

    // feature epilogue for this query
    int nidx = (int)(unsigned)(cur & 0xFFFFFFFFu);
    float4 np = p4[nidx];
    float ox = __shfl(np.x, 0), oy = __shfl(np.y, 0), oz = __shfl(np.z, 0);
    float pcx = np.x - ox, pcy = np.y - oy, pcz = np.z - oz;
    float vn = sqrtf(pcx*pcx + pcy*pcy + pcz*pcz);

    unsigned long long ak = ((unsigned long long)__float_as_uint(vn) << 32)
                          | (unsigned long long)(unsigned)(63 - lane);
    for (int s = 32; s > 0; s >>= 1) ak = u64max(ak, __shfl_xor(ak, s));
    int id1 = 63 - (int)(unsigned)(ak & 0xFFFFFFFFu);

    float a1x = __shfl(pcx, id1), a1y = __shfl(pcy, id1), a1z = __shfl(pcz, id1);
    float n1 = sqrtf(a1x*a1x + a1y*a1y + a1z*a1z) + EPSF;
    a1x /= n1; a1y /= n1; a1z /= n1;

    float sx = pcx, sy = pcy, sz = pcz;
    for (int s = 32; s > 0; s >>= 1) {
        sx += __shfl_xor(sx, s); sy += __shfl_xor(sy, s); sz += __shfl_xor(sz, s);
    }
    float a2x = sx * (1.f/64.f), a2y = sy * (1.f/64.f), a2z = sz * (1.f/64.f);
    float n2 = sqrtf(a2x*a2x + a2y*a2y + a2z*a2z) + EPSF;
    a2x /= n2; a2y /= n2; a2z /= n2;

    float a3x = a1x + 1.5f*a2x, a3y = a1y + 1.5f*a2y, a3z = a1z + 1.5f*a2z;
    float n3 = sqrtf(a3x*a3x + a3y*a3y + a3z*a3z) + EPSF;
    a3x /= n3; a3y /= n3; a3z /= n3;

    float den = vn + EPSF;
    float f1 = (pcx*a1x + pcy*a1y + pcz*a1z) / den;
    float f2 = (pcx*a2x + pcy*a2y + pcz*a2z) / den;
    float f3 = (pcx*a3x + pcy*a3y + pcz*a3z) / den;
    feat_up[q*64 + lane] = make_float4(f1, f2, f3, vn);
}

// ---------------- 5-layer MLP via bf16 MFMA + max over K ----------------
#define BROW 72
__global__ __launch_bounds__(256) void mlp_kernel(
    const float4* __restrict__ feat_up,
    const unsigned short* __restrict__ gwt,
    unsigned short* __restrict__ xb3)
{
    __shared__ __align__(16) unsigned short Blds[4][64 * BROW];
    const int lane = threadIdx.x & 63;
    const int wid  = threadIdx.x >> 6;
    const int q = blockIdx.x * 4 + wid;
    const int c = lane & 15, g = lane >> 4;
    unsigned short* B = Blds[wid];

    {
        float4 f = feat_up[q*64 + lane];
        uint2 p0;
        p0.x = (unsigned)f2bf(f.x) | ((unsigned)f2bf(f.y) << 16);
        p0.y = (unsigned)f2bf(f.z) | ((unsigned)f2bf(f.w) << 16);
        *(uint2*)&B[lane*BROW] = p0;
        *(uint2*)&B[lane*BROW + 4] = make_uint2(0, 0);
        uint4 z4 = make_uint4(0, 0, 0, 0);
        *(uint4*)&B[lane*BROW + 8]  = z4;
        *(uint4*)&B[lane*BROW + 16] = z4;
        *(uint4*)&B[lane*BROW + 24] = z4;
    }

    const unsigned short* Wl[5] = {gwt, gwt + 2048, gwt + 6144, gwt + 10240, gwt + 14336};
    f32x4 acc[4][4];

    for (int layer = 0; layer < 5; ++layer) {
        const int wstride = (layer == 0) ? 32 : 64;
        const int nks = (layer == 0) ? 1 : 2;
        #pragma unroll
        for (int mb = 0; mb < 4; ++mb)
            #pragma unroll
            for (int nb = 0; nb < 4; ++nb)
                acc[mb][nb] = (f32x4){0.f, 0.f, 0.f, 0.f};

        for (int ks = 0; ks < nks; ++ks) {
            bf16x8 af[4], bf[4];
            #pragma unroll
            for (int mb = 0; mb < 4; ++mb)
                af[mb] = *(const bf16x8*)(Wl[layer] + (mb*16 + c)*wstride + ks*32 + g*8);
            #pragma unroll
            for (int nb = 0; nb < 4; ++nb)
                bf[nb] = *(const bf16x8*)&B[(nb*16 + c)*BROW + ks*32 + g*8];
            #pragma unroll
            for (int mb = 0; mb < 4; ++mb)
                #pragma unroll
                for (int nb = 0; nb < 4; ++nb)
                    acc[mb][nb] = __builtin_amdgcn_mfma_f32_16x16x32_bf16(af[mb], bf[nb], acc[mb][nb], 0, 0, 0);
        }

        if (layer < 4) {
            #pragma unroll
            for (int mb = 0; mb < 4; ++mb) {
                #pragma unroll
                for (int nb = 0; nb < 4; ++nb) {
                    f32x4 a = acc[mb][nb];
                    float r0 = fmaxf(a[0], 0.f), r1 = fmaxf(a[1], 0.f);
                    float r2 = fmaxf(a[2], 0.f), r3 = fmaxf(a[3], 0.f);
                    uint2 pw;
                    pw.x = (unsigned)f2bf(r0) | ((unsigned)f2bf(r1) << 16);
                    pw.y = (unsigned)f2bf(r2) | ((unsigned)f2bf(r3) << 16);
                    *(uint2*)&B[(nb*16 + c)*BROW + mb*16 + g*4] = pw;
                }
            }
        }
    }

    // epilogue: ReLU + max over neighbors; write raw-view into conv3 B operand
    const int cc = q >> 7;
    const int pbase = (q & 127) << 6;
    #pragma unroll
    for (int mb = 0; mb < 4; ++mb) {
        float v[4];
        #pragma unroll
        for (int r = 0; r < 4; ++r)
            v[r] = fmaxf(fmaxf(fmaxf(acc[mb][0][r], acc[mb][1][r]),
                               fmaxf(acc[mb][2][r], acc[mb][3][r])), 0.f);
        #pragma unroll
        for (int mask = 1; mask <= 8; mask <<= 1)
            #pragma unroll
            for (int r = 0; r < 4; ++r)
                v[r] = fmaxf(v[r], __shfl_xor(v[r], mask));
        if (c == 0) {
            #pragma unroll
            for (int r = 0; r < 4; ++r) {
                const int f = mb*16 + g*4 + r;
                xb3[(size_t)(pbase + f) * 192 + cc] = f2bf(v[r]);
            }
        }
    }
}

// ---------------- conv1 (fp32 GEMV, K=4) with output stats ----------------
__global__ __launch_bounds__(256) void conv1_kernel(
    const float* __restrict__ x, const float* __restrict__ wt,
    const float* __restrict__ bias, float* __restrict__ y,
    float* __restrict__ stout)
{
    const int tid = threadIdx.x;
    const int p  = blockIdx.x * 256 + tid;
    const int o0 = blockIdx.y * 32;
    float acc[32];
    #pragma unroll
    for (int u = 0; u < 32; ++u) acc[u] = bias[o0 + u];
    #pragma unroll
    for (int c = 0; c < 4; ++c) {
        float xv = x[c * NPTS + p];
        const float* wr = wt + c * 64 + o0;
        #pragma unroll
        for (int u = 0; u < 32; ++u) acc[u] = fmaf(xv, wr[u], acc[u]);
    }
    #pragma unroll
    for (int u = 0; u < 32; ++u) y[(o0 + u) * NPTS + p] = acc[u];

    __shared__ float ps[4][32], pss[4][32];
    const int wid = tid >> 6, lane = tid & 63;
    #pragma unroll
    for (int u = 0; u < 32; ++u) {
        float s = acc[u], ss = acc[u] * acc[u];
        for (int j = 32; j > 0; j >>= 1) { s += __shfl_xor(s, j); ss += __shfl_xor(ss, j); }
        if (lane == 0) { ps[wid][u] = s; pss[wid][u] = ss; }
    }
    __syncthreads();
    if (tid < 32) {
        float S  = ps[0][tid] + ps[1][tid] + ps[2][tid] + ps[3][tid];
        float SS = pss[0][tid] + pss[1][tid] + pss[2][tid] + pss[3][tid];
        atomicAdd(&stout[o0 + tid], S);
        atomicAdd(&stout[64 + o0 + tid], SS);
    }
}

// ---------------- bnpack: y fp32 [C][N] -> BN+ReLU -> bf16 xb[p][stride] (+optional transposed copy) ----------------
__global__ __launch_bounds__(256) void bnpack_kernel(
    const float* __restrict__ y, const float* __restrict__ st,
    const float* __restrict__ gam, const float* __restrict__ bet,
    int C, int stride, int coff, unsigned short* __restrict__ xb,
    unsigned short* __restrict__ xt)
{
    __shared__ float sc[256], sh[256];
    __shared__ __align__(16) unsigned short tile[64][264];
    const int tid = threadIdx.x;
    for (int cc = tid; cc < C; cc += 256) {
        float mu  = st[cc] * (1.f / 8192.f);
        float var = st[C + cc] * (1.f / 8192.f) - mu * mu;
        float s = gam[cc] / sqrtf(var + 1e-5f);
        sc[cc] = s; sh[cc] = bet[cc] - mu * s;
    }
    __syncthreads();
    const int pl = tid & 63, g = tid >> 6;
    const int p = blockIdx.x * 64 + pl;
    for (int c0 = g * 8; c0 < C; c0 += 32) {
        unsigned pk[4];
        #pragma unroll
        for (int h = 0; h < 4; ++h) {
            float v0 = fmaxf(fmaf(y[(c0 + 2*h    ) * NPTS + p], sc[c0 + 2*h    ], sh[c0 + 2*h    ]), 0.f);
            float v1 = fmaxf(fmaf(y[(c0 + 2*h + 1) * NPTS + p], sc[c0 + 2*h + 1], sh[c0 + 2*h + 1]), 0.f);
            pk[h] = (unsigned)f2bf(v0) | ((unsigned)f2bf(v1) << 16);
        }
        *(uint4*)&tile[pl][c0] = make_uint4(pk[0], pk[1], pk[2], pk[3]);
        if (xt) {   // transposed bf16 copy [C][N] for the Gram kernel (coalesced 2B/lane runs)
            #pragma unroll
            for (int h = 0; h < 4; ++h) {
                xt[(size_t)(c0 + 2*h    ) * NPTS + p] = (unsigned short)(pk[h] & 0xFFFFu);
                xt[(size_t)(c0 + 2*h + 1) * NPTS + p] = (unsigned short)(pk[h] >> 16);
            }
        }
    }
    __syncthreads();
    const int cpr = C >> 3;                 // 16B chunks per row
    const int nch = 64 * cpr;
    for (int idx = tid; idx < nch; idx += 256) {
        int r = idx / cpr, cc = (idx - r * cpr) * 8;
        *(uint4*)&xb[(size_t)(blockIdx.x * 64 + r) * stride + coff + cc] = *(uint4*)&tile[r][cc];
    }
}

// ---------------- conv via MFMA with output-stats (conv2, conv3) ----------------
__global__ __launch_bounds__(256) void conv_mfma_kernel(
    const unsigned short* __restrict__ A, const unsigned short* __restrict__ Bx,
    const float* __restrict__ bias, int K, int M,
    float* __restrict__ y, float* __restrict__ stout)
{
    const int lane = threadIdx.x & 63;
    const int w = threadIdx.x >> 6;
    const int n0 = blockIdx.x * 256 + w * 64;
    const int m0 = blockIdx.y * 64;
    const int c = lane & 15, g = lane >> 4;

    f32x4 acc[4][4];
    #pragma unroll
    for (int mt = 0; mt < 4; ++mt)
        #pragma unroll
        for (int nt = 0; nt < 4; ++nt)
            acc[mt][nt] = (f32x4){0.f, 0.f, 0.f, 0.f};

    for (int k0 = 0; k0 < K; k0 += 32) {
        bf16x8 af[4], bf[4];
        #pragma unroll
        for (int mt = 0; mt < 4; ++mt)
            af[mt] = *(const bf16x8*)(A + (size_t)(m0 + mt*16 + c) * K + k0 + g*8);
        #pragma unroll
        for (int nt = 0; nt < 4; ++nt)
            bf[nt] = *(const bf16x8*)(Bx + (size_t)(n0 + nt*16 + c) * K + k0 + g*8);
        #pragma unroll
        for (int mt = 0; mt < 4; ++mt)
            #pragma unroll
            for (int nt = 0; nt < 4; ++nt)
                acc[mt][nt] = __builtin_amdgcn_mfma_f32_16x16x32_bf16(af[mt], bf[nt], acc[mt][nt], 0, 0, 0);
    }

    #pragma unroll
    for (int mt = 0; mt < 4; ++mt) {
        float s[4], ss[4];
        #pragma unroll
        for (int r = 0; r < 4; ++r) {
            const int o = m0 + mt*16 + g*4 + r;
            const float bv = bias[o];
            float sum = 0.f, sq = 0.f;
            #pragma unroll
            for (int nt = 0; nt < 4; ++nt) {
                float v = acc[mt][nt][r] + bv;
                y[(size_t)o * NPTS + n0 + nt*16 + c] = v;
                sum += v; sq += v * v;
            }
            s[r] = sum; ss[r] = sq;
        }
        #pragma unroll
        for (int mask = 1; mask <= 8; mask <<= 1)
            #pragma unroll
            for (int r = 0; r < 4; ++r) {
                s[r]  += __shfl_xor(s[r],  mask);
                ss[r] += __shfl_xor(ss[r], mask);
            }
        if (c == 0) {
            #pragma unroll
            for (int r = 0; r < 4; ++r) {
                const int o = m0 + mt*16 + g*4 + r;
                atomicAdd(&stout[o], s[r]);
                atomicAdd(&stout[M + o], ss[r]);
            }
        }
    }
}

// ---------------- gram4: S = Xt Xt^T over points (Xt = [256][8192] bf16), + column sums ----------------
// grid (8,8): block computes disjoint 32x32 tile of S over full K -> no atomics, no zero-init.
__global__ __launch_bounds__(256) void gram4_kernel(
    const unsigned short* __restrict__ Xt,
    float* __restrict__ S, float* __restrict__ msum)
{
    const int lane = threadIdx.x & 63;
    const int w = threadIdx.x >> 6;
    const int mt = w >> 1, nt = w & 1;
    const int m0 = blockIdx.x * 32 + mt * 16;
    const int n1 = blockIdx.y * 32 + nt * 16;
    const int c = lane & 15, g = lane >> 4;
    const bool domsum = (blockIdx.y == 0) && (nt == 0);

    f32x4 acc = (f32x4){0.f, 0.f, 0.f, 0.f};
    float ms = 0.f;
    const unsigned short* arow = Xt + (size_t)(m0 + c) * NPTS;
    const unsigned short* brow = Xt + (size_t)(n1 + c) * NPTS;
    for (int k0 = 0; k0 < NPTS; k0 += 32) {
        bf16x8 af = *(const bf16x8*)(arow + k0 + g*8);
        bf16x8 bf = *(const bf16x8*)(brow + k0 + g*8);
        acc = __builtin_amdgcn_mfma_f32_16x16x32_bf16(af, bf, acc, 0, 0, 0);
        if (domsum) {
            const unsigned short* ap = (const unsigned short*)&af;
            #pragma unroll
            for (int e = 0; e < 8; ++e) ms += bf2f(ap[e]);
        }
    }
    #pragma unroll
    for (int r = 0; r < 4; ++r)
        S[(size_t)(m0 + g*4 + r) * 256 + n1 + c] = acc[r];
    if (domsum) {
        ms += __shfl_xor(ms, 16);
        ms += __shfl_xor(ms, 32);
        if (g == 0) msum[m0 + c] = ms;
    }
}

// ---------------- solve4: per-channel BN scale/shift from input Gram ----------------
// mu_o = (w_o . msum)/N + b_o ; var_o = (w_o^T S w_o)/N - ((w_o . msum)/N)^2
__global__ __launch_bounds__(256) void solve4_kernel(
    const float* __restrict__ S, const float* __restrict__ msum,
    const unsigned short* __restrict__ w4, const float* __restrict__ bias,
    const float* __restrict__ gam, const float* __restrict__ bet,
    float* __restrict__ sc, float* __restrict__ sh)
{
    __shared__ float wf[8][256];
    const int tid = threadIdx.x;
    const int ob = blockIdx.x * 8;
    for (int m = tid; m < 8 * 256; m += 256) {
        int oo = m >> 8, j = m & 255;
        wf[oo][j] = bf2f(w4[(size_t)(ob + oo) * 256 + j]);
    }
    __syncthreads();
    const int lane = tid & 63, w = tid >> 6;
    const int jj = lane * 4;
    float4 wA = *(const float4*)&wf[w*2+0][jj];
    float4 wB = *(const float4*)&wf[w*2+1][jj];
    float ta0=0.f, ta1=0.f, ta2=0.f, ta3=0.f;
    float tb0=0.f, tb1=0.f, tb2=0.f, tb3=0.f;
    for (int i = 0; i < 256; ++i) {
        float4 sv = ((const float4*)(S + (size_t)i * 256))[lane];
        float wia = wf[w*2+0][i];
        float wib = wf[w*2+1][i];
        ta0 = fmaf(sv.x, wia, ta0); ta1 = fmaf(sv.y, wia, ta1);
        ta2 = fmaf(sv.z, wia, ta2); ta3 = fmaf(sv.w, wia, ta3);
        tb0 = fmaf(sv.x, wib, tb0); tb1 = fmaf(sv.y, wib, tb1);
        tb2 = fmaf(sv.z, wib, tb2); tb3 = fmaf(sv.w, wib, tb3);
    }
    float4 m4 = ((const float4*)msum)[lane];
    float qa = ta0*wA.x + ta1*wA.y + ta2*wA.z + ta3*wA.w;
    float qb = tb0*wB.x + tb1*wB.y + tb2*wB.z + tb3*wB.w;
    float ma = m4.x*wA.x + m4.y*wA.y + m4.z*wA.z + m4.w*wA.w;
    float mb = m4.x*wB.x + m4.y*wB.y + m4.z*wB.z + m4.w*wB.w;
    for (int j = 32; j > 0; j >>= 1) {
        qa += __shfl_xor(qa, j); qb += __shfl_xor(qb, j);
        ma += __shfl_xor(ma, j); mb += __shfl_xor(mb, j);
    }
    if (lane == 0) {
        const float invN = 1.f / 8192.f;
        int oA = ob + w*2, oB = oA + 1;
        float mdA = ma * invN, mdB = mb * invN;
        float muA = mdA + bias[oA], muB = mdB + bias[oB];
        float varA = qa * invN - mdA * mdA;
        float varB = qb * invN - mdB * mdB;
        float scA = gam[oA] / sqrtf(varA + 1e-5f);
        float scB = gam[oB] / sqrtf(varB + 1e-5f);
        sc[oA] = scA; sh[oA] = bet[oA] - muA * scA;
        sc[oB] = scB; sh[oB] = bet[oB] - muB * scB;
    }
}

// ---------------- conv4 with fused BN+ReLU epilogue (writes final output) ----------------
__global__ __launch_bounds__(256) void conv4bn_kernel(
    const unsigned short* __restrict__ A, const unsigned short* __restrict__ Bx,
    const float* __restrict__ bias, int K, int M,
    const float* __restrict__ sc, const float* __restrict__ sh,
    float* __restrict__ out)
{
    const int lane = threadIdx.x & 63;
    const int w = threadIdx.x >> 6;
    const int n0 = blockIdx.x * 256 + w * 64;
    const int m0 = blockIdx.y * 64;
    const int c = lane & 15, g = lane >> 4;

    f32x4 acc[4][4];
    #pragma unroll
    for (int mt = 0; mt < 4; ++mt)
        #pragma unroll
        for (int nt = 0; nt < 4; ++nt)
            acc[mt][nt] = (f32x4){0.f, 0.f, 0.f, 0.f};

    for (int k0 = 0; k0 < K; k0 += 32) {
        bf16x8 af[4], bf[4];
        #pragma unroll
        for (int mt = 0; mt < 4; ++mt)
            af[mt] = *(const bf16x8*)(A + (size_t)(m0 + mt*16 + c) * K + k0 + g*8);
        #pragma unroll
        for (int nt = 0; nt < 4; ++nt)
            bf[nt] = *(const bf16x8*)(Bx + (size_t)(n0 + nt*16 + c) * K + k0 + g*8);
        #pragma unroll
        for (int mt = 0; mt < 4; ++mt)
            #pragma unroll
            for (int nt = 0; nt < 4; ++nt)
                acc[mt][nt] = __builtin_amdgcn_mfma_f32_16x16x32_bf16(af[mt], bf[nt], acc[mt][nt], 0, 0, 0);
    }

    #pragma unroll
    for (int mt = 0; mt < 4; ++mt) {
        #pragma unroll
        for (int r = 0; r < 4; ++r) {
            const int o = m0 + mt*16 + g*4 + r;
            const float bv = bias[o];
            const float s = sc[o];
            const float h = sh[o];
            #pragma unroll
            for (int nt = 0; nt < 4; ++nt) {
                float v = acc[mt][nt][r] + bv;
                out[(size_t)o * NPTS + n0 + nt*16 + c] = fmaxf(fmaf(v, s, h), 0.f);
            }
        }
    }
}

extern "C" void kernel_launch(void* const* d_in, const int* in_sizes, int n_in,
                              void* d_out, int out_size, void* d_ws, size_t ws_size,
                              hipStream_t stream) {
    const float* points = (const float*)d_in[0];
    const float* gw0 = (const float*)d_in[1];
    const float* gw1 = (const float*)d_in[2];
    const float* gw2 = (const float*)d_in[3];
    const float* gw3 = (const float*)d_in[4];
    const float* gw4 = (const float*)d_in[5];
    const float* c1w = (const float*)d_in[6];  const float* c1b = (const float*)d_in[7];
    const float* bn1g = (const float*)d_in[8]; const float* bn1b = (const float*)d_in[9];
    const float* c2w = (const float*)d_in[10]; const float* c2b = (const float*)d_in[11];
    const float* bn2g = (const float*)d_in[12];const float* bn2b = (const float*)d_in[13];
    const float* c3w = (const float*)d_in[14]; const float* c3b = (const float*)d_in[15];
    const float* bn3g = (const float*)d_in[16];const float* bn3b = (const float*)d_in[17];
    const float* c4w = (const float*)d_in[18]; const float* c4b = (const float*)d_in[19];
    const float* bn4g = (const float*)d_in[20];const float* bn4b = (const float*)d_in[21];

    float* ws = (float*)d_ws;
    float* p4f    = ws + OFF_P4;
    float* featdn = ws + OFF_FEATDN;
    float* featup = ws + OFF_FEATUP;
    float* y1 = ws + OFF_Y1; float* y2 = ws + OFF_Y2; float* y3 = ws + OFF_Y3;
    float* s1 = ws + OFF_STATS + 0;
    float* s2 = ws + OFF_STATS + 128;
    float* s3 = ws + OFF_STATS + 384;
    float* wt1 = ws + OFF_WT1;
    const unsigned short* gwt = (const unsigned short*)(ws + OFF_GWT);
    const unsigned short* bw2 = (const unsigned short*)(ws + OFF_BW2);
    const unsigned short* bw3 = (const unsigned short*)(ws + OFF_BW3);
    const unsigned short* bw4 = (const unsigned short*)(ws + OFF_BW4);
    unsigned short* xb1 = (unsigned short*)(ws + OFF_XB1);
    unsigned short* xb3 = (unsigned short*)(ws + OFF_XB3);
    unsigned short* xb4 = (unsigned short*)(ws + OFF_XB4);
    unsigned short* xb4t = (unsigned short*)(ws + OFF_XB4T);
    float* S4   = ws + OFF_S4;
    float* msum = ws + OFF_MSUM;
    float* sc4  = ws + OFF_SC4;
    float* sh4  = ws + OFF_SH4;
    float* outp = (float*)d_out;

    prepwt_kernel<<<256, 256, 0, stream>>>(points, c1w, c2w, c3w, c4w,
                                           gw0, gw1, gw2, gw3, gw4, ws);
    prep_c_kernel<<<32, 256, 0, stream>>>(ws);

    knn_feat_kernel<<<1024, 512, 0, stream>>>((const float4*)p4f, (float4*)featup);
    mlp_kernel<<<2048, 256, 0, stream>>>((const float4*)featup, gwt, xb3);

    // conv1 (fp32, K=4) -> y1 + s1
    conv1_kernel<<<dim3(32, 2), 256, 0, stream>>>(featdn, wt1, c1b, y1, s1);
    // BN1+ReLU -> xb1[p][64]
    bnpack_kernel<<<128, 256, 0, stream>>>(y1, s1, bn1g, bn1b, 64, 64, 0, xb1, nullptr);
    // conv2: 128x64x8192 MFMA -> y2 + s2
    conv_mfma_kernel<<<dim3(32, 2), 256, 0, stream>>>(bw2, xb1, c2b, 64, 128, y2, s2);
    // BN2+ReLU -> xb3[p][192] cols 64..191
    bnpack_kernel<<<128, 256, 0, stream>>>(y2, s2, bn2g, bn2b, 128, 192, 64, xb3, nullptr);
    // conv3: 256x192x8192 MFMA -> y3 + s3
    conv_mfma_kernel<<<dim3(32, 4), 256, 0, stream>>>(bw3, xb3, c3b, 192, 256, y3, s3);
    // BN3+ReLU -> xb4[p][256] + transposed copy xb4t[256][8192]
    bnpack_kernel<<<128, 256, 0, stream>>>(y3, s3, bn3g, bn3b, 256, 256, 0, xb4, xb4t);
    // BN4 scale/shift from input Gram (bias cancels in var)
    gram4_kernel<<<dim3(8, 8), 256, 0, stream>>>(xb4t, S4, msum);
    solve4_kernel<<<128, 256, 0, stream>>>(S4, msum, bw4, c4b, bn4g, bn4b, sc4, sh4);
    // conv4 with fused BN+ReLU -> final output
    conv4bn_kernel<<<dim3(32, 16), 256, 0, stream>>>(bw4, xb4, c4b, 256, 1024, sc4, sh4, outp);
}

// Round 5
// 350.035 us; speedup vs baseline: 1.2023x; 1.2023x over previous
//
#include <hip/hip_runtime.h>
#include <hip/hip_bf16.h>

#define NPTS 8192
#define KNN 64
#define EPSF 1e-7f

// ---------------- workspace layout (float offsets) ----------------
#define OFF_P4      0              // packed (x,y,z,rr) float4 per point: 4*N
#define OFF_STATS   32768          // s1:+0(128) s2:+128(256) s3:+384(512) s4:+896(2048) = 2944
#define OFF_PART    36012          // 32 blocks x 2 u64 = 128 floats
#define OFF_FEATDN  36864          // N*4 -> 69632
#define OFF_WT1     69632          // 4*64 fp32 transposed -> 69888
#define OFF_GWT     69888          // MLP bf16 weights: 18432 shorts = 9216 -> 79104
#define OFF_BW2     79104          // c2w bf16: 8192 shorts = 4096 -> 83200
#define OFF_BW3     83200          // c3w bf16: 49152 shorts = 24576 -> 107776
#define OFF_BW4     107776         // c4w bf16: 262144 shorts = 131072 -> 238848
#define OFF_XB1     238848         // bf16 [8192][64]  = 262144 fl -> 500992
#define OFF_XB3     500992         // bf16 [8192][192] = 786432 fl -> 1287424
#define OFF_XB4     1287424        // bf16 [8192][256] = 1048576 fl -> 2336000
#define OFF_Y1      2336000        // 64*N fp32 -> 2860288
#define OFF_Y2      2860288        // 128*N fp32 -> 3908864
#define OFF_Y3      3908864        // 256*N fp32 -> 6006016
#define OFF_FEATUP  6006016        // N*K*4 fp32 -> 8103168 (~30.9 MB)

typedef __bf16 bf16x8 __attribute__((ext_vector_type(8)));
typedef float  f32x4  __attribute__((ext_vector_type(4)));

__device__ __forceinline__ unsigned f2u(float f) {
    unsigned u = __float_as_uint(f);
    return ((int)u >= 0) ? (u | 0x80000000u) : ~u;
}
__device__ __forceinline__ float key_to_f(unsigned long long k) {
    unsigned v = (unsigned)(k >> 32);
    unsigned ob = (v & 0x80000000u) ? (v ^ 0x80000000u) : ~v;
    return __uint_as_float(ob);
}
// native RNE f32->bf16 (compiler pairs adjacent casts into v_cvt_pk_bf16_f32)
__device__ __forceinline__ unsigned short f2bf(float x) {
    union { __bf16 h; unsigned short s; } u;
    u.h = (__bf16)x;
    return u.s;
}
__device__ __forceinline__ unsigned packbf2(float lo, float hi) {
    return (unsigned)f2bf(lo) | ((unsigned)f2bf(hi) << 16);
}
__device__ __forceinline__ unsigned long long u64min(unsigned long long a, unsigned long long b){ return a < b ? a : b; }
__device__ __forceinline__ unsigned long long u64max(unsigned long long a, unsigned long long b){ return a < b ? b : a; }

__device__ __forceinline__ unsigned long long sort_merge(
    unsigned long long key, unsigned long long cur, int lane)
{
    #pragma unroll
    for (int k = 2; k <= 64; k <<= 1) {
        #pragma unroll
        for (int j = k >> 1; j > 0; j >>= 1) {
            unsigned long long o = __shfl_xor(key, j);
            bool up = ((lane & k) == 0);
            bool lower = ((lane & j) == 0);
            key = (lower == up) ? u64min(key, o) : u64max(key, o);
        }
    }
    unsigned long long rev = __shfl(key, 63 - lane);
    unsigned long long m = u64min(cur, rev);
    #pragma unroll
    for (int j = 32; j > 0; j >>= 1) {
        unsigned long long o = __shfl_xor(m, j);
        m = ((lane & j) == 0) ? u64min(m, o) : u64max(m, o);
    }
    return m;
}

// ---------------- prep A + weight prep (fused; disjoint work) ----------------
__global__ __launch_bounds__(256) void prepwt_kernel(
    const float* __restrict__ points,
    const float* __restrict__ c1w, const float* __restrict__ c2w,
    const float* __restrict__ c3w, const float* __restrict__ c4w,
    const float* __restrict__ gw0, const float* __restrict__ gw1,
    const float* __restrict__ gw2, const float* __restrict__ gw3,
    const float* __restrict__ gw4,
    float* __restrict__ ws)
{
    const int t = blockIdx.x * 256 + threadIdx.x;
    const int T = 256 * 256;
    for (int m = t; m < 2944; m += T) ws[OFF_STATS + m] = 0.f;
    for (int m = t; m < 64*4; m += T) { int o = m >> 2, c = m & 3; ws[OFF_WT1 + c*64 + o] = c1w[m]; }

    unsigned short* bw2 = (unsigned short*)(ws + OFF_BW2);
    for (int m = t; m < 128*64; m += T)   bw2[m] = f2bf(c2w[m]);
    unsigned short* bw3 = (unsigned short*)(ws + OFF_BW3);
    for (int m = t; m < 256*192; m += T)  bw3[m] = f2bf(c3w[m]);
    unsigned short* bw4 = (unsigned short*)(ws + OFF_BW4);
    for (int m = t; m < 1024*256; m += T) bw4[m] = f2bf(c4w[m]);

    unsigned short* gwt = (unsigned short*)(ws + OFF_GWT);
    for (int m = t; m < 2048; m += T) {          // gw0T padded [64][32]
        int o = m >> 5, i = m & 31;
        gwt[m] = (i < 4) ? f2bf(gw0[i*64 + o]) : (unsigned short)0;
    }
    const float* gsrc[4] = {gw1, gw2, gw3, gw4};
    for (int l = 0; l < 4; ++l) {
        const float* g = gsrc[l];
        unsigned short* dst = gwt + 2048 + l*4096;
        for (int m = t; m < 4096; m += T) { int o = m >> 6, i = m & 63; dst[m] = f2bf(g[i*64 + o]); }
    }

    // ---- prep_a part (blocks 0..31 only; block-uniform branch) ----
    if (blockIdx.x < 32) {
        const int n = blockIdx.x * 256 + threadIdx.x;
        float x = points[3*n+0], y = points[3*n+1], z = points[3*n+2];
        float rr = x*x + y*y + z*z;
        ((float4*)(ws + OFF_P4))[n] = make_float4(x, y, z, rr);
        float vn = sqrtf(rr);
        unsigned b = __float_as_uint(vn);
        unsigned long long mxk = ((unsigned long long)b << 32) | (unsigned long long)(0xFFFFFFFFu - (unsigned)n);
        unsigned long long mnk = ((unsigned long long)b << 32) | (unsigned long long)(unsigned)n;
        for (int j = 32; j > 0; j >>= 1) {
            mxk = u64max(mxk, __shfl_xor(mxk, j));
            mnk = u64min(mnk, __shfl_xor(mnk, j));
        }
        __shared__ unsigned long long smx[4], smn[4];
        int wid = threadIdx.x >> 6;
        if ((threadIdx.x & 63) == 0) { smx[wid] = mxk; smn[wid] = mnk; }
        __syncthreads();
        if (threadIdx.x == 0) {
            unsigned long long MX = 0ull, MN = ~0ull;
            for (int i = 0; i < 4; ++i) { MX = u64max(MX, smx[i]); MN = u64min(MN, smn[i]); }
            unsigned long long* parts = (unsigned long long*)(ws + OFF_PART);
            parts[2*blockIdx.x + 0] = MX;
            parts[2*blockIdx.x + 1] = MN;
        }
    }
}

// ---------------- prep C: feat_down (prep_b reduce folded into per-block prologue) ----------------
__global__ __launch_bounds__(256) void prep_c_kernel(float* __restrict__ ws)
{
    __shared__ float av[9];
    const int tid = threadIdx.x;
    if (tid < 64) {
        const unsigned long long* parts = (const unsigned long long*)(ws + OFF_PART);
        unsigned long long mxk = (tid < 32) ? parts[2*tid + 0] : 0ull;
        unsigned long long mnk = (tid < 32) ? parts[2*tid + 1] : ~0ull;
        for (int j = 32; j > 0; j >>= 1) {
            mxk = u64max(mxk, __shfl_xor(mxk, j));
            mnk = u64min(mnk, __shfl_xor(mnk, j));
        }
        if (tid == 0) {
            int i1 = (int)(0xFFFFFFFFu - (unsigned)(mxk & 0xFFFFFFFFu));
            int i2 = (int)(unsigned)(mnk & 0xFFFFFFFFu);
            float4 p1 = ((const float4*)(ws + OFF_P4))[i1];
            float4 p2 = ((const float4*)(ws + OFF_P4))[i2];
            float n1 = sqrtf(p1.x*p1.x + p1.y*p1.y + p1.z*p1.z) + EPSF;
            float a1x = p1.x/n1, a1y = p1.y/n1, a1z = p1.z/n1;
            float n2 = sqrtf(p2.x*p2.x + p2.y*p2.y + p2.z*p2.z) + EPSF;
            float a2x = p2.x/n2, a2y = p2.y/n2, a2z = p2.z/n2;
            float a3x = a1x + 1.5f*a2x, a3y = a1y + 1.5f*a2y, a3z = a1z + 1.5f*a2z;
            float n3 = sqrtf(a3x*a3x + a3y*a3y + a3z*a3z) + EPSF;
            a3x /= n3; a3y /= n3; a3z /= n3;
            av[0]=a1x; av[1]=a1y; av[2]=a1z;
            av[3]=a2x; av[4]=a2y; av[5]=a2z;
            av[6]=a3x; av[7]=a3y; av[8]=a3z;
        }
    }
    __syncthreads();
    const int n = blockIdx.x * 256 + tid;
    float4 v = ((const float4*)(ws + OFF_P4))[n];
    float vn = sqrtf(v.w);
    float den = vn + EPSF;
    float f1 = (v.x*av[0] + v.y*av[1] + v.z*av[2]) / den;
    float f2 = (v.x*av[3] + v.y*av[4] + v.z*av[5]) / den;
    float f3 = (v.x*av[6] + v.y*av[7] + v.z*av[8]) / den;
    float4* f4 = (float4*)(ws + OFF_FEATDN + 4*n);
    *f4 = make_float4(f1, f2, f3, vn);
}

// ---------------- KNN + local rotation-invariant features ----------------
// 1 query per wave, 8 waves/block, 40 KB LDS -> 4 blocks/CU.
// Ordering key: e = |p|^2 - 2 q.p  (= dist^2 - |q|^2, constant shift per query
// -> identical ordering & ties). 2 candidates per lane per iteration for ILP.
__global__ __launch_bounds__(512) void knn_feat_kernel(
    const float4* __restrict__ p4, float4* __restrict__ feat_up)
{
    __shared__ __align__(16) float4 scand[2048];
    __shared__ unsigned long long queue[8][128];
    const int lane = threadIdx.x & 63;
    const int wid  = threadIdx.x >> 6;
    const int q = blockIdx.x * 8 + wid;

    const float4 qa = p4[q];
    unsigned long long cur = ~0ull;
    float ke = __builtin_inff();
    int qc = 0;
    unsigned long long* Q = queue[wid];

    for (int base = 0; base < NPTS; base += 2048) {
        __syncthreads();
        for (int t = threadIdx.x; t < 2048; t += 512) scand[t] = p4[base + t];
        __syncthreads();
        #pragma unroll 2
        for (int sub = 0; sub < 2048; sub += 128) {
            float4 cd0 = scand[sub + lane];
            float4 cd1 = scand[sub + 64 + lane];
            float dot0 = fmaf(qa.x, cd0.x, fmaf(qa.y, cd0.y, qa.z * cd0.z));
            float dot1 = fmaf(qa.x, cd1.x, fmaf(qa.y, cd1.y, qa.z * cd1.z));
            float e0 = fmaf(-2.f, dot0, cd0.w);
            float e1 = fmaf(-2.f, dot1, cd1.w);
            bool p0 = e0 < ke;
            bool p1 = e1 < ke;          // stale ke after a flush is conservative (exactness kept)
            unsigned long long m0 = __ballot(p0);
            unsigned long long m1 = __ballot(p1);
            if (m0) {
                int prefix = __builtin_amdgcn_mbcnt_hi((unsigned)(m0 >> 32),
                              __builtin_amdgcn_mbcnt_lo((unsigned)m0, 0));
                if (p0) Q[qc + prefix] = ((unsigned long long)f2u(e0) << 32)
                                       | (unsigned long long)(unsigned)(base + sub + lane);
                qc += __popcll(m0);
                if (qc >= 64) {
                    qc -= 64;
                    cur = sort_merge(Q[qc + lane], cur, lane);
                    ke = key_to_f(__shfl(cur, 63));
                }
            }
            if (m1) {
                int prefix = __builtin_amdgcn_mbcnt_hi((unsigned)(m1 >> 32),
                              __builtin_amdgcn_mbcnt_lo((unsigned)m1, 0));
                if (p1) Q[qc + prefix] = ((unsigned long long)f2u(e1) << 32)
                                       | (unsigned long long)(unsigned)(base + sub + 64 + lane);
                qc += __popcll(m1);
                if (qc >= 64) {
                    qc -= 64;
                    cur = sort_merge(Q[qc + lane], cur, lane);
                    ke = key_to_f(__shfl(cur, 63));
                }
            }
        }
    }
    cur = sort_merge((lane < qc) ? Q[lane] : ~0ull, cur, lane);

    // feature epilogue for this query (indices only; distances recomputed from coords)
    int nidx = (int)(unsigned)(cur & 0xFFFFFFFFu);
    float4 np = p4[nidx];
    float ox = __shfl(np.x, 0), oy = __shfl(np.y, 0), oz = __shfl(np.z, 0);
    float pcx = np.x - ox, pcy = np.y - oy, pcz = np.z - oz;
    float vn = sqrtf(pcx*pcx + pcy*pcy + pcz*pcz);

    unsigned long long ak = ((unsigned long long)__float_as_uint(vn) << 32)
                          | (unsigned long long)(unsigned)(63 - lane);
    for (int s = 32; s > 0; s >>= 1) ak = u64max(ak, __shfl_xor(ak, s));
    int id1 = 63 - (int)(unsigned)(ak & 0xFFFFFFFFu);

    float a1x = __shfl(pcx, id1), a1y = __shfl(pcy, id1), a1z = __shfl(pcz, id1);
    float n1 = sqrtf(a1x*a1x + a1y*a1y + a1z*a1z) + EPSF;
    a1x /= n1; a1y /= n1; a1z /= n1;

    float sx = pcx, sy = pcy, sz = pcz;
    for (int s = 32; s > 0; s >>= 1) {
        sx += __shfl_xor(sx, s); sy += __shfl_xor(sy, s); sz += __shfl_xor(sz, s);
    }
    float a2x = sx * (1.f/64.f), a2y = sy * (1.f/64.f), a2z = sz * (1.f/64.f);
    float n2 = sqrtf(a2x*a2x + a2y*a2y + a2z*a2z) + EPSF;
    a2x /= n2; a2y /= n2; a2z /= n2;

    float a3x = a1x + 1.5f*a2x, a3y = a1y + 1.5f*a2y, a3z = a1z + 1.5f*a2z;
    float n3 = sqrtf(a3x*a3x + a3y*a3y + a3z*a3z) + EPSF;
    a3x /= n3; a3y /= n3; a3z /= n3;

    float den = vn + EPSF;
    float f1 = (pcx*a1x + pcy*a1y + pcz*a1z) / den;
    float f2 = (pcx*a2x + pcy*a2y + pcz*a2z) / den;
    float f3 = (pcx*a3x + pcy*a3y + pcz*a3z) / den;
    feat_up[q*64 + lane] = make_float4(f1, f2, f3, vn);
}

// ---------------- 5-layer MLP via bf16 MFMA + max over K ----------------
#define BROW 72
__global__ __launch_bounds__(256) void mlp_kernel(
    const float4* __restrict__ feat_up,
    const unsigned short* __restrict__ gwt,
    unsigned short* __restrict__ xb3)
{
    __shared__ __align__(16) unsigned short Blds[4][64 * BROW];
    const int lane = threadIdx.x & 63;
    const int wid  = threadIdx.x >> 6;
    const int q = blockIdx.x * 4 + wid;
    const int c = lane & 15, g = lane >> 4;
    unsigned short* B = Blds[wid];

    {
        float4 f = feat_up[q*64 + lane];
        uint2 p0;
        p0.x = packbf2(f.x, f.y);
        p0.y = packbf2(f.z, f.w);
        *(uint2*)&B[lane*BROW] = p0;
        *(uint2*)&B[lane*BROW + 4] = make_uint2(0, 0);
        uint4 z4 = make_uint4(0, 0, 0, 0);
        *(uint4*)&B[lane*BROW + 8]  = z4;
        *(uint4*)&B[lane*BROW + 16] = z4;
        *(uint4*)&B[lane*BROW + 24] = z4;
    }

    const unsigned short* Wl[5] = {gwt, gwt + 2048, gwt + 6144, gwt + 10240, gwt + 14336};
    f32x4 acc[4][4];

    for (int layer = 0; layer < 5; ++layer) {
        const int wstride = (layer == 0) ? 32 : 64;
        const int nks = (layer == 0) ? 1 : 2;
        #pragma unroll
        for (int mb = 0; mb < 4; ++mb)
            #pragma unroll
            for (int nb = 0; nb < 4; ++nb)
                acc[mb][nb] = (f32x4){0.f, 0.f, 0.f, 0.f};

        for (int ks = 0; ks < nks; ++ks) {
            bf16x8 af[4], bf[4];
            #pragma unroll
            for (int mb = 0; mb < 4; ++mb)
                af[mb] = *(const bf16x8*)(Wl[layer] + (mb*16 + c)*wstride + ks*32 + g*8);
            #pragma unroll
            for (int nb = 0; nb < 4; ++nb)
                bf[nb] = *(const bf16x8*)&B[(nb*16 + c)*BROW + ks*32 + g*8];
            #pragma unroll
            for (int mb = 0; mb < 4; ++mb)
                #pragma unroll
                for (int nb = 0; nb < 4; ++nb)
                    acc[mb][nb] = __builtin_amdgcn_mfma_f32_16x16x32_bf16(af[mb], bf[nb], acc[mb][nb], 0, 0, 0);
        }

        if (layer < 4) {
            #pragma unroll
            for (int mb = 0; mb < 4; ++mb) {
                #pragma unroll
                for (int nb = 0; nb < 4; ++nb) {
                    f32x4 a = acc[mb][nb];
                    uint2 pw;
                    pw.x = packbf2(fmaxf(a[0], 0.f), fmaxf(a[1], 0.f));
                    pw.y = packbf2(fmaxf(a[2], 0.f), fmaxf(a[3], 0.f));
                    *(uint2*)&B[(nb*16 + c)*BROW + mb*16 + g*4] = pw;
                }
            }
        }
    }

    // epilogue: ReLU + max over neighbors; write raw-view into conv3 B operand
    const int cc = q >> 7;
    const int pbase = (q & 127) << 6;
    #pragma unroll
    for (int mb = 0; mb < 4; ++mb) {
        float v[4];
        #pragma unroll
        for (int r = 0; r < 4; ++r)
            v[r] = fmaxf(fmaxf(fmaxf(acc[mb][0][r], acc[mb][1][r]),
                               fmaxf(acc[mb][2][r], acc[mb][3][r])), 0.f);
        #pragma unroll
        for (int mask = 1; mask <= 8; mask <<= 1)
            #pragma unroll
            for (int r = 0; r < 4; ++r)
                v[r] = fmaxf(v[r], __shfl_xor(v[r], mask));
        if (c == 0) {
            #pragma unroll
            for (int r = 0; r < 4; ++r) {
                const int f = mb*16 + g*4 + r;
                xb3[(size_t)(pbase + f) * 192 + cc] = f2bf(v[r]);
            }
        }
    }
}

// ---------------- conv1 (fp32 GEMV, K=4) with output stats ----------------
__global__ __launch_bounds__(256) void conv1_kernel(
    const float* __restrict__ x, const float* __restrict__ wt,
    const float* __restrict__ bias, float* __restrict__ y,
    float* __restrict__ stout)
{
    const int tid = threadIdx.x;
    const int p  = blockIdx.x * 256 + tid;
    const int o0 = blockIdx.y * 32;
    float acc[32];
    #pragma unroll
    for (int u = 0; u < 32; ++u) acc[u] = bias[o0 + u];
    #pragma unroll
    for (int c = 0; c < 4; ++c) {
        float xv = x[c * NPTS + p];
        const float* wr = wt + c * 64 + o0;
        #pragma unroll
        for (int u = 0; u < 32; ++u) acc[u] = fmaf(xv, wr[u], acc[u]);
    }
    #pragma unroll
    for (int u = 0; u < 32; ++u) y[(o0 + u) * NPTS + p] = acc[u];

    __shared__ float ps[4][32], pss[4][32];
    const int wid = tid >> 6, lane = tid & 63;
    #pragma unroll
    for (int u = 0; u < 32; ++u) {
        float s = acc[u], ss = acc[u] * acc[u];
        for (int j = 32; j > 0; j >>= 1) { s += __shfl_xor(s, j); ss += __shfl_xor(ss, j); }
        if (lane == 0) { ps[wid][u] = s; pss[wid][u] = ss; }
    }
    __syncthreads();
    if (tid < 32) {
        float S  = ps[0][tid] + ps[1][tid] + ps[2][tid] + ps[3][tid];
        float SS = pss[0][tid] + pss[1][tid] + pss[2][tid] + pss[3][tid];
        atomicAdd(&stout[o0 + tid], S);
        atomicAdd(&stout[64 + o0 + tid], SS);
    }
}

// ---------------- bnpack: y fp32 [C][N] -> BN+ReLU -> bf16 xb[p][stride] at col offset ----------------
__global__ __launch_bounds__(256) void bnpack_kernel(
    const float* __restrict__ y, const float* __restrict__ st,
    const float* __restrict__ gam, const float* __restrict__ bet,
    int C, int stride, int coff, unsigned short* __restrict__ xb)
{
    __shared__ float sc[256], sh[256];
    __shared__ __align__(16) unsigned short tile[64][264];
    const int tid = threadIdx.x;
    for (int cc = tid; cc < C; cc += 256) {
        float mu  = st[cc] * (1.f / 8192.f);
        float var = st[C + cc] * (1.f / 8192.f) - mu * mu;
        float s = gam[cc] / sqrtf(var + 1e-5f);
        sc[cc] = s; sh[cc] = bet[cc] - mu * s;
    }
    __syncthreads();
    const int pl = tid & 63, g = tid >> 6;
    const int p = blockIdx.x * 64 + pl;
    for (int c0 = g * 8; c0 < C; c0 += 32) {
        unsigned pk[4];
        #pragma unroll
        for (int h = 0; h < 4; ++h) {
            float v0 = fmaxf(fmaf(y[(c0 + 2*h    ) * NPTS + p], sc[c0 + 2*h    ], sh[c0 + 2*h    ]), 0.f);
            float v1 = fmaxf(fmaf(y[(c0 + 2*h + 1) * NPTS + p], sc[c0 + 2*h + 1], sh[c0 + 2*h + 1]), 0.f);
            pk[h] = packbf2(v0, v1);
        }
        *(uint4*)&tile[pl][c0] = make_uint4(pk[0], pk[1], pk[2], pk[3]);
    }
    __syncthreads();
    const int cpr = C >> 3;                 // 16B chunks per row
    const int nch = 64 * cpr;
    for (int idx = tid; idx < nch; idx += 256) {
        int r = idx / cpr, cc = (idx - r * cpr) * 8;
        *(uint4*)&xb[(size_t)(blockIdx.x * 64 + r) * stride + coff + cc] = *(uint4*)&tile[r][cc];
    }
}

// ---------------- conv via MFMA: y[M][N] = A[M][K](bf16) x Xb[N][K](bf16)^T + bias ----------------
__global__ __launch_bounds__(256) void conv_mfma_kernel(
    const unsigned short* __restrict__ A, const unsigned short* __restrict__ Bx,
    const float* __restrict__ bias, int K, int M,
    float* __restrict__ y, float* __restrict__ stout)
{
    const int lane = threadIdx.x & 63;
    const int w = threadIdx.x >> 6;
    const int n0 = blockIdx.x * 256 + w * 64;
    const int m0 = blockIdx.y * 64;
    const int c = lane & 15, g = lane >> 4;

    f32x4 acc[4][4];
    #pragma unroll
    for (int mt = 0; mt < 4; ++mt)
        #pragma unroll
        for (int nt = 0; nt < 4; ++nt)
            acc[mt][nt] = (f32x4){0.f, 0.f, 0.f, 0.f};

    for (int k0 = 0; k0 < K; k0 += 32) {
        bf16x8 af[4], bf[4];
        #pragma unroll
        for (int mt = 0; mt < 4; ++mt)
            af[mt] = *(const bf16x8*)(A + (size_t)(m0 + mt*16 + c) * K + k0 + g*8);
        #pragma unroll
        for (int nt = 0; nt < 4; ++nt)
            bf[nt] = *(const bf16x8*)(Bx + (size_t)(n0 + nt*16 + c) * K + k0 + g*8);
        #pragma unroll
        for (int mt = 0; mt < 4; ++mt)
            #pragma unroll
            for (int nt = 0; nt < 4; ++nt)
                acc[mt][nt] = __builtin_amdgcn_mfma_f32_16x16x32_bf16(af[mt], bf[nt], acc[mt][nt], 0, 0, 0);
    }

    #pragma unroll
    for (int mt = 0; mt < 4; ++mt) {
        float s[4], ss[4];
        #pragma unroll
        for (int r = 0; r < 4; ++r) {
            const int o = m0 + mt*16 + g*4 + r;
            const float bv = bias[o];
            float sum = 0.f, sq = 0.f;
            #pragma unroll
            for (int nt = 0; nt < 4; ++nt) {
                float v = acc[mt][nt][r] + bv;
                y[(size_t)o * NPTS + n0 + nt*16 + c] = v;
                sum += v; sq += v * v;
            }
            s[r] = sum; ss[r] = sq;
        }
        #pragma unroll
        for (int mask = 1; mask <= 8; mask <<= 1)
            #pragma unroll
            for (int r = 0; r < 4; ++r) {
                s[r]  += __shfl_xor(s[r],  mask);
                ss[r] += __shfl_xor(ss[r], mask);
            }
        if (c == 0) {
            #pragma unroll
            for (int r = 0; r < 4; ++r) {
                const int o = m0 + mt*16 + g*4 + r;
                atomicAdd(&stout[o], s[r]);
                atomicAdd(&stout[M + o], ss[r]);
            }
        }
    }
}

// ---------------- final BN + ReLU (in place on d_out), float4-vectorized ----------------
__global__ __launch_bounds__(256) void bnrelu_kernel(
    const float4* y, const float* __restrict__ st,
    const float* __restrict__ g, const float* __restrict__ b,
    float4* out, int C)
{
    int idx = blockIdx.x * 256 + threadIdx.x;   // float4 index
    int c = idx >> 11;   // N/4 = 2048 float4 per channel row
    float mu  = st[c] * (1.f / 8192.f);
    float var = st[C + c] * (1.f / 8192.f) - mu * mu;
    float scale = g[c] / sqrtf(var + 1e-5f);
    float sh = b[c] - mu * scale;
    float4 v = y[idx];
    v.x = fmaxf(fmaf(v.x, scale, sh), 0.f);
    v.y = fmaxf(fmaf(v.y, scale, sh), 0.f);
    v.z = fmaxf(fmaf(v.z, scale, sh), 0.f);
    v.w = fmaxf(fmaf(v.w, scale, sh), 0.f);
    out[idx] = v;
}

extern "C" void kernel_launch(void* const* d_in, const int* in_sizes, int n_in,
                              void* d_out, int out_size, void* d_ws, size_t ws_size,
                              hipStream_t stream) {
    const float* points = (const float*)d_in[0];
    const float* gw0 = (const float*)d_in[1];
    const float* gw1 = (const float*)d_in[2];
    const float* gw2 = (const float*)d_in[3];
    const float* gw3 = (const float*)d_in[4];
    const float* gw4 = (const float*)d_in[5];
    const float* c1w = (const float*)d_in[6];  const float* c1b = (const float*)d_in[7];
    const float* bn1g = (const float*)d_in[8]; const float* bn1b = (const float*)d_in[9];
    const float* c2w = (const float*)d_in[10]; const float* c2b = (const float*)d_in[11];
    const float* bn2g = (const float*)d_in[12];const float* bn2b = (const float*)d_in[13];
    const float* c3w = (const float*)d_in[14]; const float* c3b = (const float*)d_in[15];
    const float* bn3g = (const float*)d_in[16];const float* bn3b = (const float*)d_in[17];
    const float* c4w = (const float*)d_in[18]; const float* c4b = (const float*)d_in[19];
    const float* bn4g = (const float*)d_in[20];const float* bn4b = (const float*)d_in[21];

    float* ws = (float*)d_ws;
    float* p4f    = ws + OFF_P4;
    float* featdn = ws + OFF_FEATDN;
    float* featup = ws + OFF_FEATUP;
    float* y1 = ws + OFF_Y1; float* y2 = ws + OFF_Y2; float* y3 = ws + OFF_Y3;
    float* s1 = ws + OFF_STATS + 0;
    float* s2 = ws + OFF_STATS + 128;
    float* s3 = ws + OFF_STATS + 384;
    float* s4 = ws + OFF_STATS + 896;
    float* wt1 = ws + OFF_WT1;
    const unsigned short* gwt = (const unsigned short*)(ws + OFF_GWT);
    const unsigned short* bw2 = (const unsigned short*)(ws + OFF_BW2);
    const unsigned short* bw3 = (const unsigned short*)(ws + OFF_BW3);
    const unsigned short* bw4 = (const unsigned short*)(ws + OFF_BW4);
    unsigned short* xb1 = (unsigned short*)(ws + OFF_XB1);
    unsigned short* xb3 = (unsigned short*)(ws + OFF_XB3);
    unsigned short* xb4 = (unsigned short*)(ws + OFF_XB4);
    float* outp = (float*)d_out;

    prepwt_kernel<<<256, 256, 0, stream>>>(points, c1w, c2w, c3w, c4w,
                                           gw0, gw1, gw2, gw3, gw4, ws);
    prep_c_kernel<<<32, 256, 0, stream>>>(ws);

    knn_feat_kernel<<<1024, 512, 0, stream>>>((const float4*)p4f, (float4*)featup);
    mlp_kernel<<<2048, 256, 0, stream>>>((const float4*)featup, gwt, xb3);

    // conv1 (fp32, K=4) -> y1 + s1
    conv1_kernel<<<dim3(32, 2), 256, 0, stream>>>(featdn, wt1, c1b, y1, s1);
    // BN1+ReLU -> xb1[p][64]
    bnpack_kernel<<<128, 256, 0, stream>>>(y1, s1, bn1g, bn1b, 64, 64, 0, xb1);
    // conv2: 128x64x8192 MFMA -> y2 + s2
    conv_mfma_kernel<<<dim3(32, 2), 256, 0, stream>>>(bw2, xb1, c2b, 64, 128, y2, s2);
    // BN2+ReLU -> xb3[p][192] cols 64..191
    bnpack_kernel<<<128, 256, 0, stream>>>(y2, s2, bn2g, bn2b, 128, 192, 64, xb3);
    // conv3: 256x192x8192 MFMA -> y3 + s3
    conv_mfma_kernel<<<dim3(32, 4), 256, 0, stream>>>(bw3, xb3, c3b, 192, 256, y3, s3);
    // BN3+ReLU -> xb4[p][256]
    bnpack_kernel<<<128, 256, 0, stream>>>(y3, s3, bn3g, bn3b, 256, 256, 0, xb4);
    // conv4: 1024x256x8192 MFMA -> d_out (pre-BN) + s4
    conv_mfma_kernel<<<dim3(32, 16), 256, 0, stream>>>(bw4, xb4, c4b, 256, 1024, outp, s4);
    // final BN4 + ReLU in place
    bnrelu_kernel<<<8192, 256, 0, stream>>>((const float4*)outp, s4, bn4g, bn4b, (float4*)outp, 1024);
}

// Round 7
// 332.849 us; speedup vs baseline: 1.2644x; 1.0516x over previous
//
#include <hip/hip_runtime.h>
#include <hip/hip_bf16.h>

#define NPTS 8192
#define KNN 64
#define EPSF 1e-7f

// ---------------- workspace layout (float offsets) ----------------
#define OFF_P4      0              // packed (x,y,z,rr) float4 per point: 4*N
#define OFF_STATS   32768          // s1:+0(128) s2:+128(256) s3:+384(512) s4:+896(2048) = 2944
#define OFF_PART    36012          // 32 blocks x 2 u64 = 128 floats
#define OFF_FEATDN  36864          // N*4 -> 69632 (raw-view source for conv1)
#define OFF_WT1     69632          // 4*64 fp32 transposed -> 69888
#define OFF_GWT     69888          // MLP bf16 weights: 18432 shorts = 9216 -> 79104
#define OFF_BW2     79104          // c2w bf16: 8192 shorts = 4096 -> 83200
#define OFF_BW3     83200          // c3w bf16: 49152 shorts = 24576 -> 107776
#define OFF_BW4     107776         // c4w bf16: 262144 shorts = 131072 -> 238848
#define OFF_XB3V    238848         // bf16 raw-view emb_up [8192][64] = 262144 fl -> 500992
#define OFF_Y1      2336000        // 64*N fp32 -> 2860288
#define OFF_Y2      2860288        // 128*N fp32 -> 3908864
#define OFF_Y3      3908864        // 256*N fp32 -> 6006016
#define OFF_FEATUP  6006016        // N*K*4 fp32 -> 8103168 (~30.9 MB)

typedef __bf16 bf16x8 __attribute__((ext_vector_type(8)));
typedef float  f32x4  __attribute__((ext_vector_type(4)));

__device__ __forceinline__ unsigned f2u(float f) {
    unsigned u = __float_as_uint(f);
    return ((int)u >= 0) ? (u | 0x80000000u) : ~u;
}
__device__ __forceinline__ float key_to_f(unsigned long long k) {
    unsigned v = (unsigned)(k >> 32);
    unsigned ob = (v & 0x80000000u) ? (v ^ 0x80000000u) : ~v;
    return __uint_as_float(ob);
}
// native RNE f32->bf16
__device__ __forceinline__ unsigned short f2bf(float x) {
    union { __bf16 h; unsigned short s; } u;
    u.h = (__bf16)x;
    return u.s;
}
__device__ __forceinline__ unsigned packbf2(float lo, float hi) {
    return (unsigned)f2bf(lo) | ((unsigned)f2bf(hi) << 16);
}
__device__ __forceinline__ unsigned long long u64min(unsigned long long a, unsigned long long b){ return a < b ? a : b; }
__device__ __forceinline__ unsigned long long u64max(unsigned long long a, unsigned long long b){ return a < b ? b : a; }

__device__ __forceinline__ unsigned long long sort_merge(
    unsigned long long key, unsigned long long cur, int lane)
{
    #pragma unroll
    for (int k = 2; k <= 64; k <<= 1) {
        #pragma unroll
        for (int j = k >> 1; j > 0; j >>= 1) {
            unsigned long long o = __shfl_xor(key, j);
            bool up = ((lane & k) == 0);
            bool lower = ((lane & j) == 0);
            key = (lower == up) ? u64min(key, o) : u64max(key, o);
        }
    }
    unsigned long long rev = __shfl(key, 63 - lane);
    unsigned long long m = u64min(cur, rev);
    #pragma unroll
    for (int j = 32; j > 0; j >>= 1) {
        unsigned long long o = __shfl_xor(m, j);
        m = ((lane & j) == 0) ? u64min(m, o) : u64max(m, o);
    }
    return m;
}

// ---------------- prep A + weight prep (fused; disjoint work) ----------------
__global__ __launch_bounds__(256) void prepwt_kernel(
    const float* __restrict__ points,
    const float* __restrict__ c1w, const float* __restrict__ c2w,
    const float* __restrict__ c3w, const float* __restrict__ c4w,
    const float* __restrict__ gw0, const float* __restrict__ gw1,
    const float* __restrict__ gw2, const float* __restrict__ gw3,
    const float* __restrict__ gw4,
    float* __restrict__ ws)
{
    const int t = blockIdx.x * 256 + threadIdx.x;
    const int T = 256 * 256;
    for (int m = t; m < 2944; m += T) ws[OFF_STATS + m] = 0.f;
    for (int m = t; m < 64*4; m += T) { int o = m >> 2, c = m & 3; ws[OFF_WT1 + c*64 + o] = c1w[m]; }

    unsigned short* bw2 = (unsigned short*)(ws + OFF_BW2);
    for (int m = t; m < 128*64; m += T)   bw2[m] = f2bf(c2w[m]);
    unsigned short* bw3 = (unsigned short*)(ws + OFF_BW3);
    for (int m = t; m < 256*192; m += T)  bw3[m] = f2bf(c3w[m]);
    unsigned short* bw4 = (unsigned short*)(ws + OFF_BW4);
    for (int m = t; m < 1024*256; m += T) bw4[m] = f2bf(c4w[m]);

    unsigned short* gwt = (unsigned short*)(ws + OFF_GWT);
    for (int m = t; m < 2048; m += T) {          // gw0T padded [64][32]
        int o = m >> 5, i = m & 31;
        gwt[m] = (i < 4) ? f2bf(gw0[i*64 + o]) : (unsigned short)0;
    }
    const float* gsrc[4] = {gw1, gw2, gw3, gw4};
    for (int l = 0; l < 4; ++l) {
        const float* g = gsrc[l];
        unsigned short* dst = gwt + 2048 + l*4096;
        for (int m = t; m < 4096; m += T) { int o = m >> 6, i = m & 63; dst[m] = f2bf(g[i*64 + o]); }
    }

    // ---- prep_a part (blocks 0..31 only; block-uniform branch) ----
    if (blockIdx.x < 32) {
        const int n = blockIdx.x * 256 + threadIdx.x;
        float x = points[3*n+0], y = points[3*n+1], z = points[3*n+2];
        float rr = x*x + y*y + z*z;
        ((float4*)(ws + OFF_P4))[n] = make_float4(x, y, z, rr);
        float vn = sqrtf(rr);
        unsigned b = __float_as_uint(vn);
        unsigned long long mxk = ((unsigned long long)b << 32) | (unsigned long long)(0xFFFFFFFFu - (unsigned)n);
        unsigned long long mnk = ((unsigned long long)b << 32) | (unsigned long long)(unsigned)n;
        for (int j = 32; j > 0; j >>= 1) {
            mxk = u64max(mxk, __shfl_xor(mxk, j));
            mnk = u64min(mnk, __shfl_xor(mnk, j));
        }
        __shared__ unsigned long long smx[4], smn[4];
        int wid = threadIdx.x >> 6;
        if ((threadIdx.x & 63) == 0) { smx[wid] = mxk; smn[wid] = mnk; }
        __syncthreads();
        if (threadIdx.x == 0) {
            unsigned long long MX = 0ull, MN = ~0ull;
            for (int i = 0; i < 4; ++i) { MX = u64max(MX, smx[i]); MN = u64min(MN, smn[i]); }
            unsigned long long* parts = (unsigned long long*)(ws + OFF_PART);
            parts[2*blockIdx.x + 0] = MX;
            parts[2*blockIdx.x + 1] = MN;
        }
    }
}

// ---------------- prep C: feat_down (prep_b reduce folded into per-block prologue) ----------------
// NOTE: conv1 consumes feat_down via the reference's RAW-RESHAPE view
// (channel c, position p = featdn_flat[c*8192+p]) — a cross-block scramble,
// so conv1 CANNOT be fused here (needs a global barrier). Verified by R6's failure.
__global__ __launch_bounds__(256) void prep_c_kernel(float* __restrict__ ws)
{
    __shared__ float av[9];
    const int tid = threadIdx.x;
    if (tid < 64) {
        const unsigned long long* parts = (const unsigned long long*)(ws + OFF_PART);
        unsigned long long mxk = (tid < 32) ? parts[2*tid + 0] : 0ull;
        unsigned long long mnk = (tid < 32) ? parts[2*tid + 1] : ~0ull;
        for (int j = 32; j > 0; j >>= 1) {
            mxk = u64max(mxk, __shfl_xor(mxk, j));
            mnk = u64min(mnk, __shfl_xor(mnk, j));
        }
        if (tid == 0) {
            int i1 = (int)(0xFFFFFFFFu - (unsigned)(mxk & 0xFFFFFFFFu));
            int i2 = (int)(unsigned)(mnk & 0xFFFFFFFFu);
            float4 p1 = ((const float4*)(ws + OFF_P4))[i1];
            float4 p2 = ((const float4*)(ws + OFF_P4))[i2];
            float n1 = sqrtf(p1.x*p1.x + p1.y*p1.y + p1.z*p1.z) + EPSF;
            float a1x = p1.x/n1, a1y = p1.y/n1, a1z = p1.z/n1;
            float n2 = sqrtf(p2.x*p2.x + p2.y*p2.y + p2.z*p2.z) + EPSF;
            float a2x = p2.x/n2, a2y = p2.y/n2, a2z = p2.z/n2;
            float a3x = a1x + 1.5f*a2x, a3y = a1y + 1.5f*a2y, a3z = a1z + 1.5f*a2z;
            float n3 = sqrtf(a3x*a3x + a3y*a3y + a3z*a3z) + EPSF;
            a3x /= n3; a3y /= n3; a3z /= n3;
            av[0]=a1x; av[1]=a1y; av[2]=a1z;
            av[3]=a2x; av[4]=a2y; av[5]=a2z;
            av[6]=a3x; av[7]=a3y; av[8]=a3z;
        }
    }
    __syncthreads();
    const int n = blockIdx.x * 256 + tid;
    float4 v = ((const float4*)(ws + OFF_P4))[n];
    float vn = sqrtf(v.w);
    float den = vn + EPSF;
    float f1 = (v.x*av[0] + v.y*av[1] + v.z*av[2]) / den;
    float f2 = (v.x*av[3] + v.y*av[4] + v.z*av[5]) / den;
    float f3 = (v.x*av[6] + v.y*av[7] + v.z*av[8]) / den;
    float4* f4 = (float4*)(ws + OFF_FEATDN + 4*n);
    *f4 = make_float4(f1, f2, f3, vn);
}

// ---------------- KNN + local rotation-invariant features ----------------
// 1 query per wave, 8 waves/block, 40 KB LDS -> 4 blocks/CU.
__global__ __launch_bounds__(512) void knn_feat_kernel(
    const float4* __restrict__ p4, float4* __restrict__ feat_up)
{
    __shared__ __align__(16) float4 scand[2048];
    __shared__ unsigned long long queue[8][128];
    const int lane = threadIdx.x & 63;
    const int wid  = threadIdx.x >> 6;
    const int q = blockIdx.x * 8 + wid;

    const float4 qa = p4[q];
    unsigned long long cur = ~0ull;
    float ke = __builtin_inff();
    int qc = 0;
    unsigned long long* Q = queue[wid];

    for (int base = 0; base < NPTS; base += 2048) {
        __syncthreads();
        for (int t = threadIdx.x; t < 2048; t += 512) scand[t] = p4[base + t];
        __syncthreads();
        #pragma unroll 2
        for (int sub = 0; sub < 2048; sub += 128) {
            float4 cd0 = scand[sub + lane];
            float4 cd1 = scand[sub + 64 + lane];
            float dot0 = fmaf(qa.x, cd0.x, fmaf(qa.y, cd0.y, qa.z * cd0.z));
            float dot1 = fmaf(qa.x, cd1.x, fmaf(qa.y, cd1.y, qa.z * cd1.z));
            float e0 = fmaf(-2.f, dot0, cd0.w);
            float e1 = fmaf(-2.f, dot1, cd1.w);
            bool p0 = e0 < ke;
            bool p1 = e1 < ke;
            unsigned long long m0 = __ballot(p0);
            unsigned long long m1 = __ballot(p1);
            if (m0) {
                int prefix = __builtin_amdgcn_mbcnt_hi((unsigned)(m0 >> 32),
                              __builtin_amdgcn_mbcnt_lo((unsigned)m0, 0));
                if (p0) Q[qc + prefix] = ((unsigned long long)f2u(e0) << 32)
                                       | (unsigned long long)(unsigned)(base + sub + lane);
                qc += __popcll(m0);
                if (qc >= 64) {
                    qc -= 64;
                    cur = sort_merge(Q[qc + lane], cur, lane);
                    ke = key_to_f(__shfl(cur, 63));
                }
            }
            if (m1) {
                int prefix = __builtin_amdgcn_mbcnt_hi((unsigned)(m1 >> 32),
                              __builtin_amdgcn_mbcnt_lo((unsigned)m1, 0));
                if (p1) Q[qc + prefix] = ((unsigned long long)f2u(e1) << 32)
                                       | (unsigned long long)(unsigned)(base + sub + 64 + lane);
                qc += __popcll(m1);
                if (qc >= 64) {
                    qc -= 64;
                    cur = sort_merge(Q[qc + lane], cur, lane);
                    ke = key_to_f(__shfl(cur, 63));
                }
            }
        }
    }
    cur = sort_merge((lane < qc) ? Q[lane] : ~0ull, cur, lane);

    // feature epilogue
    int nidx = (int)(unsigned)(cur & 0xFFFFFFFFu);
    float4 np = p4[nidx];
    float ox = __shfl(np.x, 0), oy = __shfl(np.y, 0), oz = __shfl(np.z, 0);
    float pcx = np.x - ox, pcy = np.y - oy, pcz = np.z - oz;
    float vn = sqrtf(pcx*pcx + pcy*pcy + pcz*pcz);

    unsigned long long ak = ((unsigned long long)__float_as_uint(vn) << 32)
                          | (unsigned long long)(unsigned)(63 - lane);
    for (int s = 32; s > 0; s >>= 1) ak = u64max(ak, __shfl_xor(ak, s));
    int id1 = 63 - (int)(unsigned)(ak & 0xFFFFFFFFu);

    float a1x = __shfl(pcx, id1), a1y = __shfl(pcy, id1), a1z = __shfl(pcz, id1);
    float n1 = sqrtf(a1x*a1x + a1y*a1y + a1z*a1z) + EPSF;
    a1x /= n1; a1y /= n1; a1z /= n1;

    float sx = pcx, sy = pcy, sz = pcz;
    for (int s = 32; s > 0; s >>= 1) {
        sx += __shfl_xor(sx, s); sy += __shfl_xor(sy, s); sz += __shfl_xor(sz, s);
    }
    float a2x = sx * (1.f/64.f), a2y = sy * (1.f/64.f), a2z = sz * (1.f/64.f);
    float n2 = sqrtf(a2x*a2x + a2y*a2y + a2z*a2z) + EPSF;
    a2x /= n2; a2y /= n2; a2z /= n2;

    float a3x = a1x + 1.5f*a2x, a3y = a1y + 1.5f*a2y, a3z = a1z + 1.5f*a2z;
    float n3 = sqrtf(a3x*a3x + a3y*a3y + a3z*a3z) + EPSF;
    a3x /= n3; a3y /= n3; a3z /= n3;

    float den = vn + EPSF;
    float f1 = (pcx*a1x + pcy*a1y + pcz*a1z) / den;
    float f2 = (pcx*a2x + pcy*a2y + pcz*a2z) / den;
    float f3 = (pcx*a3x + pcy*a3y + pcz*a3z) / den;
    feat_up[q*64 + lane] = make_float4(f1, f2, f3, vn);
}

// ---------------- 5-layer MLP via bf16 MFMA + max over K ----------------
// Epilogue writes emb_up's RAW-RESHAPE view into xb3v[8192][64]:
// for (point q, feature f): cc = q>>7, p = (q&127)*64 + f  ->  xb3v[p*64 + cc].
#define BROW 72
__global__ __launch_bounds__(256) void mlp_kernel(
    const float4* __restrict__ feat_up,
    const unsigned short* __restrict__ gwt,
    unsigned short* __restrict__ xb3v)
{
    __shared__ __align__(16) unsigned short Blds[4][64 * BROW];
    const int lane = threadIdx.x & 63;
    const int wid  = threadIdx.x >> 6;
    const int q = blockIdx.x * 4 + wid;
    const int c = lane & 15, g = lane >> 4;
    unsigned short* B = Blds[wid];

    {
        float4 f = feat_up[q*64 + lane];
        uint2 p0;
        p0.x = packbf2(f.x, f.y);
        p0.y = packbf2(f.z, f.w);
        *(uint2*)&B[lane*BROW] = p0;
        *(uint2*)&B[lane*BROW + 4] = make_uint2(0, 0);
        uint4 z4 = make_uint4(0, 0, 0, 0);
        *(uint4*)&B[lane*BROW + 8]  = z4;
        *(uint4*)&B[lane*BROW + 16] = z4;
        *(uint4*)&B[lane*BROW + 24] = z4;
    }

    const unsigned short* Wl[5] = {gwt, gwt + 2048, gwt + 6144, gwt + 10240, gwt + 14336};
    f32x4 acc[4][4];

    for (int layer = 0; layer < 5; ++layer) {
        const int wstride = (layer == 0) ? 32 : 64;
        const int nks = (layer == 0) ? 1 : 2;
        #pragma unroll
        for (int mb = 0; mb < 4; ++mb)
            #pragma unroll
            for (int nb = 0; nb < 4; ++nb)
                acc[mb][nb] = (f32x4){0.f, 0.f, 0.f, 0.f};

        for (int ks = 0; ks < nks; ++ks) {
            bf16x8 af[4], bf[4];
            #pragma unroll
            for (int mb = 0; mb < 4; ++mb)
                af[mb] = *(const bf16x8*)(Wl[layer] + (mb*16 + c)*wstride + ks*32 + g*8);
            #pragma unroll
            for (int nb = 0; nb < 4; ++nb)
                bf[nb] = *(const bf16x8*)&B[(nb*16 + c)*BROW + ks*32 + g*8];
            #pragma unroll
            for (int mb = 0; mb < 4; ++mb)
                #pragma unroll
                for (int nb = 0; nb < 4; ++nb)
                    acc[mb][nb] = __builtin_amdgcn_mfma_f32_16x16x32_bf16(af[mb], bf[nb], acc[mb][nb], 0, 0, 0);
        }

        if (layer < 4) {
            #pragma unroll
            for (int mb = 0; mb < 4; ++mb) {
                #pragma unroll
                for (int nb = 0; nb < 4; ++nb) {
                    f32x4 a = acc[mb][nb];
                    uint2 pw;
                    pw.x = packbf2(fmaxf(a[0], 0.f), fmaxf(a[1], 0.f));
                    pw.y = packbf2(fmaxf(a[2], 0.f), fmaxf(a[3], 0.f));
                    *(uint2*)&B[(nb*16 + c)*BROW + mb*16 + g*4] = pw;
                }
            }
        }
    }

    // epilogue: ReLU + max over neighbors; write raw-view array
    const int cc = q >> 7;
    const int pbase = (q & 127) << 6;
    #pragma unroll
    for (int mb = 0; mb < 4; ++mb) {
        float v[4];
        #pragma unroll
        for (int r = 0; r < 4; ++r)
            v[r] = fmaxf(fmaxf(fmaxf(acc[mb][0][r], acc[mb][1][r]),
                               fmaxf(acc[mb][2][r], acc[mb][3][r])), 0.f);
        #pragma unroll
        for (int mask = 1; mask <= 8; mask <<= 1)
            #pragma unroll
            for (int r = 0; r < 4; ++r)
                v[r] = fmaxf(v[r], __shfl_xor(v[r], mask));
        if (c == 0) {
            #pragma unroll
            for (int r = 0; r < 4; ++r) {
                const int f = mb*16 + g*4 + r;
                xb3v[(size_t)(pbase + f) * 64 + cc] = f2bf(v[r]);
            }
        }
    }
}

// ---------------- conv1 (fp32 GEMV, K=4, raw-view input) with output stats ----------------
__global__ __launch_bounds__(256) void conv1_kernel(
    const float* __restrict__ x, const float* __restrict__ wt,
    const float* __restrict__ bias, float* __restrict__ y,
    float* __restrict__ stout)
{
    const int tid = threadIdx.x;
    const int p  = blockIdx.x * 256 + tid;
    const int o0 = blockIdx.y * 32;
    float acc[32];
    #pragma unroll
    for (int u = 0; u < 32; ++u) acc[u] = bias[o0 + u];
    #pragma unroll
    for (int c = 0; c < 4; ++c) {
        float xv = x[c * NPTS + p];          // raw-reshape view of featdn [N][4]
        const float* wr = wt + c * 64 + o0;
        #pragma unroll
        for (int u = 0; u < 32; ++u) acc[u] = fmaf(xv, wr[u], acc[u]);
    }
    #pragma unroll
    for (int u = 0; u < 32; ++u) y[(o0 + u) * NPTS + p] = acc[u];

    __shared__ float ps[4][32], pss[4][32];
    const int wid = tid >> 6, lane = tid & 63;
    #pragma unroll
    for (int u = 0; u < 32; ++u) {
        float s = acc[u], ss = acc[u] * acc[u];
        for (int j = 32; j > 0; j >>= 1) { s += __shfl_xor(s, j); ss += __shfl_xor(ss, j); }
        if (lane == 0) { ps[wid][u] = s; pss[wid][u] = ss; }
    }
    __syncthreads();
    if (tid < 32) {
        float S  = ps[0][tid] + ps[1][tid] + ps[2][tid] + ps[3][tid];
        float SS = pss[0][tid] + pss[1][tid] + pss[2][tid] + pss[3][tid];
        atomicAdd(&stout[o0 + tid], S);
        atomicAdd(&stout[64 + o0 + tid], SS);
    }
}

// ---------------- convbn: MFMA conv with previous-layer BN+ReLU+bf16 applied on the fly ----------------
// B cols [0, Kdir) from Bdir (bf16 [N][Kdir]); cols [Kdir, K) from yprev fp32 [Cprev][N]
// with BN + ReLU + RNE-bf16 — bit-identical to the old bnpack->xb->conv path.
__global__ __launch_bounds__(256) void convbn_kernel(
    const unsigned short* __restrict__ A,
    const unsigned short* __restrict__ Bdir, int Kdir,
    const float* __restrict__ yprev,
    const float* __restrict__ stp, const float* __restrict__ gam, const float* __restrict__ bet,
    const float* __restrict__ bias, int K, int M,
    float* __restrict__ yout, float* __restrict__ stout)
{
    __shared__ float sc[256], sh[256];
    const int tid = threadIdx.x;
    const int Cp = K - Kdir;
    for (int cc = tid; cc < Cp; cc += 256) {
        float mu  = stp[cc] * (1.f / 8192.f);
        float var = stp[Cp + cc] * (1.f / 8192.f) - mu * mu;
        float s = gam[cc] / sqrtf(var + 1e-5f);
        sc[cc] = s; sh[cc] = bet[cc] - mu * s;
    }
    __syncthreads();

    const int lane = tid & 63;
    const int w = tid >> 6;
    const int n0 = blockIdx.x * 256 + w * 64;
    const int m0 = blockIdx.y * 64;
    const int c = lane & 15, g = lane >> 4;

    f32x4 acc[4][4];
    #pragma unroll
    for (int mt = 0; mt < 4; ++mt)
        #pragma unroll
        for (int nt = 0; nt < 4; ++nt)
            acc[mt][nt] = (f32x4){0.f, 0.f, 0.f, 0.f};

    for (int k0 = 0; k0 < K; k0 += 32) {
        bf16x8 af[4], bf[4];
        #pragma unroll
        for (int mt = 0; mt < 4; ++mt)
            af[mt] = *(const bf16x8*)(A + (size_t)(m0 + mt*16 + c) * K + k0 + g*8);
        if (k0 + 32 <= Kdir) {
            #pragma unroll
            for (int nt = 0; nt < 4; ++nt)
                bf[nt] = *(const bf16x8*)(Bdir + (size_t)(n0 + nt*16 + c) * Kdir + k0 + g*8);
        } else {
            const int ch0 = k0 - Kdir + g*8;
            #pragma unroll
            for (int nt = 0; nt < 4; ++nt) {
                const int pt = n0 + nt*16 + c;
                bf16x8 r;
                #pragma unroll
                for (int j = 0; j < 8; ++j) {
                    float vv = fmaxf(fmaf(yprev[(size_t)(ch0 + j) * NPTS + pt],
                                          sc[ch0 + j], sh[ch0 + j]), 0.f);
                    r[j] = (__bf16)vv;
                }
                bf[nt] = r;
            }
        }
        #pragma unroll
        for (int mt = 0; mt < 4; ++mt)
            #pragma unroll
            for (int nt = 0; nt < 4; ++nt)
                acc[mt][nt] = __builtin_amdgcn_mfma_f32_16x16x32_bf16(af[mt], bf[nt], acc[mt][nt], 0, 0, 0);
    }

    #pragma unroll
    for (int mt = 0; mt < 4; ++mt) {
        float s[4], ss[4];
        #pragma unroll
        for (int r = 0; r < 4; ++r) {
            const int o = m0 + mt*16 + g*4 + r;
            const float bv = bias[o];
            float sum = 0.f, sq = 0.f;
            #pragma unroll
            for (int nt = 0; nt < 4; ++nt) {
                float v = acc[mt][nt][r] + bv;
                yout[(size_t)o * NPTS + n0 + nt*16 + c] = v;
                sum += v; sq += v * v;
            }
            s[r] = sum; ss[r] = sq;
        }
        #pragma unroll
        for (int mask = 1; mask <= 8; mask <<= 1)
            #pragma unroll
            for (int r = 0; r < 4; ++r) {
                s[r]  += __shfl_xor(s[r],  mask);
                ss[r] += __shfl_xor(ss[r], mask);
            }
        if (c == 0) {
            #pragma unroll
            for (int r = 0; r < 4; ++r) {
                const int o = m0 + mt*16 + g*4 + r;
                atomicAdd(&stout[o], s[r]);
                atomicAdd(&stout[M + o], ss[r]);
            }
        }
    }
}

// ---------------- final BN + ReLU (in place on d_out), float4-vectorized ----------------
__global__ __launch_bounds__(256) void bnrelu_kernel(
    const float4* y, const float* __restrict__ st,
    const float* __restrict__ g, const float* __restrict__ b,
    float4* out, int C)
{
    int idx = blockIdx.x * 256 + threadIdx.x;   // float4 index
    int c = idx >> 11;   // N/4 = 2048 float4 per channel row
    float mu  = st[c] * (1.f / 8192.f);
    float var = st[C + c] * (1.f / 8192.f) - mu * mu;
    float scale = g[c] / sqrtf(var + 1e-5f);
    float sh = b[c] - mu * scale;
    float4 v = y[idx];
    v.x = fmaxf(fmaf(v.x, scale, sh), 0.f);
    v.y = fmaxf(fmaf(v.y, scale, sh), 0.f);
    v.z = fmaxf(fmaf(v.z, scale, sh), 0.f);
    v.w = fmaxf(fmaf(v.w, scale, sh), 0.f);
    out[idx] = v;
}

extern "C" void kernel_launch(void* const* d_in, const int* in_sizes, int n_in,
                              void* d_out, int out_size, void* d_ws, size_t ws_size,
                              hipStream_t stream) {
    const float* points = (const float*)d_in[0];
    const float* gw0 = (const float*)d_in[1];
    const float* gw1 = (const float*)d_in[2];
    const float* gw2 = (const float*)d_in[3];
    const float* gw3 = (const float*)d_in[4];
    const float* gw4 = (const float*)d_in[5];
    const float* c1w = (const float*)d_in[6];  const float* c1b = (const float*)d_in[7];
    const float* bn1g = (const float*)d_in[8]; const float* bn1b = (const float*)d_in[9];
    const float* c2w = (const float*)d_in[10]; const float* c2b = (const float*)d_in[11];
    const float* bn2g = (const float*)d_in[12];const float* bn2b = (const float*)d_in[13];
    const float* c3w = (const float*)d_in[14]; const float* c3b = (const float*)d_in[15];
    const float* bn3g = (const float*)d_in[16];const float* bn3b = (const float*)d_in[17];
    const float* c4w = (const float*)d_in[18]; const float* c4b = (const float*)d_in[19];
    const float* bn4g = (const float*)d_in[20];const float* bn4b = (const float*)d_in[21];

    float* ws = (float*)d_ws;
    float* p4f    = ws + OFF_P4;
    float* featdn = ws + OFF_FEATDN;
    float* featup = ws + OFF_FEATUP;
    float* y1 = ws + OFF_Y1; float* y2 = ws + OFF_Y2; float* y3 = ws + OFF_Y3;
    float* s1 = ws + OFF_STATS + 0;
    float* s2 = ws + OFF_STATS + 128;
    float* s3 = ws + OFF_STATS + 384;
    float* s4 = ws + OFF_STATS + 896;
    float* wt1 = ws + OFF_WT1;
    const unsigned short* gwt = (const unsigned short*)(ws + OFF_GWT);
    const unsigned short* bw2 = (const unsigned short*)(ws + OFF_BW2);
    const unsigned short* bw3 = (const unsigned short*)(ws + OFF_BW3);
    const unsigned short* bw4 = (const unsigned short*)(ws + OFF_BW4);
    unsigned short* xb3v = (unsigned short*)(ws + OFF_XB3V);
    float* outp = (float*)d_out;

    prepwt_kernel<<<256, 256, 0, stream>>>(points, c1w, c2w, c3w, c4w,
                                           gw0, gw1, gw2, gw3, gw4, ws);
    prep_c_kernel<<<32, 256, 0, stream>>>(ws);

    knn_feat_kernel<<<1024, 512, 0, stream>>>((const float4*)p4f, (float4*)featup);
    mlp_kernel<<<2048, 256, 0, stream>>>((const float4*)featup, gwt, xb3v);

    // conv1 (fp32, K=4, raw-view) -> y1 + s1
    conv1_kernel<<<dim3(32, 2), 256, 0, stream>>>(featdn, wt1, c1b, y1, s1);
    // conv2 with BN1 on the fly: 128x64x8192 -> y2 + s2
    convbn_kernel<<<dim3(32, 2), 256, 0, stream>>>(bw2, nullptr, 0, y1, s1, bn1g, bn1b,
                                                   c2b, 64, 128, y2, s2);
    // conv3: cols 0..63 direct from xb3v (raw-view emb), cols 64..191 = BN2(y2)
    convbn_kernel<<<dim3(32, 4), 256, 0, stream>>>(bw3, xb3v, 64, y2, s2, bn2g, bn2b,
                                                   c3b, 192, 256, y3, s3);
    // conv4 with BN3 on the fly -> d_out (pre-BN4) + s4
    convbn_kernel<<<dim3(32, 16), 256, 0, stream>>>(bw4, nullptr, 0, y3, s3, bn3g, bn3b,
                                                    c4b, 256, 1024, outp, s4);
    // final BN4 + ReLU in place
    bnrelu_kernel<<<8192, 256, 0, stream>>>((const float4*)outp, s4, bn4g, bn4b, (float4*)outp, 1024);
}